// Round 1
// baseline (345.558 us; speedup 1.0000x reference)
//
#include <hip/hip_runtime.h>

using u16 = unsigned short;
using u32 = unsigned int;

typedef __bf16 bf16x8 __attribute__((ext_vector_type(8)));
typedef float  f32x4  __attribute__((ext_vector_type(4)));

__device__ __forceinline__ u16 f2bf(float f) {
    u32 u = __float_as_uint(f);
    u32 r = u + 0x7fffu + ((u >> 16) & 1u);
    return (u16)(r >> 16);
}
__device__ __forceinline__ float bf2f(u16 u) {
    return __uint_as_float(((u32)u) << 16);
}
__device__ __forceinline__ float gelu_f(float x) {
    return 0.5f * x * (1.0f + erff(x * 0.70710678118654752440f));
}

// ---------------- f32 -> bf16 conversion ----------------
__global__ __launch_bounds__(256) void cvt_kernel(const float* __restrict__ in,
                                                  u16* __restrict__ out, int n4) {
    int i = blockIdx.x * 256 + threadIdx.x;
    int stride = gridDim.x * 256;
    for (; i < n4; i += stride) {
        float4 v = ((const float4*)in)[i];
        ushort4 o;
        o.x = f2bf(v.x); o.y = f2bf(v.y); o.z = f2bf(v.z); o.w = f2bf(v.w);
        ((ushort4*)out)[i] = o;
    }
}

// ---------------- NT GEMM: C[m][n] = sum_k A[m][k]*B[n][k] ----------------
// MODE 0: write bf16 H^T per graph: HT[graph][n][node]   (graph = tm>>7, node = local row)
// MODE 1: write bf16 gelu(C + bias[n]) row-major [m][n]  (AGG1 -> next layer input)
// MODE 2: write f32 (C + bias[n]) * timemask row-major into d_out (AGG2)
template<int KTOT, int MODE>
__global__ __launch_bounds__(256) void gemm_nt(
    const u16* __restrict__ A, const u16* __restrict__ B,
    long aBatch, long bBatch,
    u16* __restrict__ outU, float* __restrict__ outF,
    const float* __restrict__ bias, const int* __restrict__ valid)
{
    constexpr int LS = 40;  // LDS row stride (32 + 8 pad) in bf16 elems
    __shared__ __align__(16) u16 As[128 * LS];
    __shared__ __align__(16) u16 Bs[128 * LS];

    const int tid  = threadIdx.x;
    const int lane = tid & 63;
    const int w    = tid >> 6;
    const int wm   = w & 1, wn = w >> 1;
    const int z    = blockIdx.z;
    const int tm   = blockIdx.x * 128;
    const int tn   = blockIdx.y * 128;

    const u16* Ag = A + (size_t)z * aBatch + (size_t)tm * KTOT;
    const u16* Bg = B + (size_t)z * bBatch + (size_t)tn * KTOT;

    const int r0 = tid >> 2;          // staging row (0..63), second chunk row+64
    const int kc = (tid & 3) * 8;     // staging k offset (elems)
    const int fr = lane & 15;         // fragment row (A) / col (B)
    const int ko = (lane >> 4) * 8;   // fragment k offset

    f32x4 acc[4][4] = {};

    for (int k0 = 0; k0 < KTOT; k0 += 32) {
        *(uint4*)&As[(r0     ) * LS + kc] = *(const uint4*)&Ag[(size_t)(r0     ) * KTOT + k0 + kc];
        *(uint4*)&As[(r0 + 64) * LS + kc] = *(const uint4*)&Ag[(size_t)(r0 + 64) * KTOT + k0 + kc];
        *(uint4*)&Bs[(r0     ) * LS + kc] = *(const uint4*)&Bg[(size_t)(r0     ) * KTOT + k0 + kc];
        *(uint4*)&Bs[(r0 + 64) * LS + kc] = *(const uint4*)&Bg[(size_t)(r0 + 64) * KTOT + k0 + kc];
        __syncthreads();
        bf16x8 af[4], bf_[4];
        #pragma unroll
        for (int i = 0; i < 4; ++i) {
            af[i]  = *(const bf16x8*)&As[(wm * 64 + i * 16 + fr) * LS + ko];
            bf_[i] = *(const bf16x8*)&Bs[(wn * 64 + i * 16 + fr) * LS + ko];
        }
        #pragma unroll
        for (int i = 0; i < 4; ++i)
            #pragma unroll
            for (int j = 0; j < 4; ++j)
                acc[i][j] = __builtin_amdgcn_mfma_f32_16x16x32_bf16(af[i], bf_[j], acc[i][j], 0, 0, 0);
        __syncthreads();
    }

    const int crow = (lane >> 4) * 4;
    const int ccol = lane & 15;

    if (MODE == 0) {
        u16* H = outU + (size_t)(tm >> 7) * (512 * 128);
        #pragma unroll
        for (int i = 0; i < 4; ++i) {
            int node0 = wm * 64 + i * 16 + crow;
            #pragma unroll
            for (int j = 0; j < 4; ++j) {
                int n = tn + wn * 64 + j * 16 + ccol;
                ushort4 o;
                o.x = f2bf(acc[i][j][0]);
                o.y = f2bf(acc[i][j][1]);
                o.z = f2bf(acc[i][j][2]);
                o.w = f2bf(acc[i][j][3]);
                *(ushort4*)&H[(size_t)n * 128 + node0] = o;
            }
        }
    } else if (MODE == 1) {
        #pragma unroll
        for (int i = 0; i < 4; ++i) {
            int m0 = z * 128 + wm * 64 + i * 16 + crow;
            #pragma unroll
            for (int j = 0; j < 4; ++j) {
                int n = tn + wn * 64 + j * 16 + ccol;
                float bv = bias[n];
                #pragma unroll
                for (int jj = 0; jj < 4; ++jj) {
                    float v = gelu_f(acc[i][j][jj] + bv);
                    outU[(size_t)(m0 + jj) * 512 + n] = f2bf(v);
                }
            }
        }
    } else {
        int b = z >> 5, t = z & 31;
        float msk = (t < valid[b]) ? 1.0f : 0.0f;
        #pragma unroll
        for (int i = 0; i < 4; ++i) {
            int m0 = z * 128 + wm * 64 + i * 16 + crow;
            #pragma unroll
            for (int j = 0; j < 4; ++j) {
                int n = tn + wn * 64 + j * 16 + ccol;
                float bv = bias[n];
                #pragma unroll
                for (int jj = 0; jj < 4; ++jj) {
                    outF[(size_t)(m0 + jj) * 512 + n] = (acc[i][j][jj] + bv) * msk;
                }
            }
        }
    }
}

// ---------------- per-node attention scores from bf16 H^T ----------------
// s_src[g*128+node] = sum_f HT[g][f][node] * a_src[f]  (same for dst)
__global__ __launch_bounds__(256) void scores_kernel(const u16* __restrict__ HT,
                                                     const float* __restrict__ a_s,
                                                     const float* __restrict__ a_d,
                                                     float* __restrict__ ss,
                                                     float* __restrict__ sd) {
    __shared__ float t1[256], t2[256];
    int z = blockIdx.x, tid = threadIdx.x;
    int node = tid & 127, h = tid >> 7;
    const u16* H = HT + (size_t)z * 65536 + node;
    float s1 = 0.f, s2 = 0.f;
    for (int f = h * 256; f < h * 256 + 256; ++f) {
        float v = bf2f(H[(size_t)f * 128]);
        s1 += v * a_s[f];
        s2 += v * a_d[f];
    }
    t1[tid] = s1; t2[tid] = s2;
    __syncthreads();
    if (tid < 128) {
        ss[z * 128 + tid] = t1[tid] + t1[tid + 128];
        sd[z * 128 + tid] = t2[tid] + t2[tid + 128];
    }
}

// ---------------- dense per-graph softmax -> bf16 alpha[dst][src] ----------------
__global__ __launch_bounds__(256) void alpha_kernel(const int* __restrict__ ei,
                                                    const float* __restrict__ ss,
                                                    const float* __restrict__ sd,
                                                    u16* __restrict__ alpha) {
    __shared__ float cnt[128 * 128];   // 64 KB
    __shared__ float s_s[128], s_d[128];
    int z = blockIdx.x, tid = threadIdx.x;
    for (int i = tid; i < 16384; i += 256) cnt[i] = 0.f;
    if (tid < 128) {
        s_s[tid] = ss[z * 128 + tid];
        s_d[tid] = sd[z * 128 + tid];
    }
    __syncthreads();
    const int* e = ei + (size_t)z * 4096;
    for (int i = tid; i < 2048; i += 256) {
        int s = e[i], d = e[2048 + i];
        atomicAdd(&cnt[d * 128 + s], 1.0f);
    }
    if (tid < 128) atomicAdd(&cnt[tid * 128 + tid], 1.0f);  // self loop
    __syncthreads();
    int lane = tid & 63, wv = tid >> 6;
    for (int d = wv; d < 128; d += 4) {
        float sdv = s_d[d];
        float c0 = cnt[d * 128 + lane], c1 = cnt[d * 128 + 64 + lane];
        float e0 = s_s[lane] + sdv;       e0 = e0 > 0.f ? e0 : 0.2f * e0;
        float e1 = s_s[64 + lane] + sdv;  e1 = e1 > 0.f ? e1 : 0.2f * e1;
        float m = fmaxf(c0 > 0.f ? e0 : -1e30f, c1 > 0.f ? e1 : -1e30f);
        #pragma unroll
        for (int o = 32; o; o >>= 1) m = fmaxf(m, __shfl_xor(m, o));
        float p0 = c0 > 0.f ? c0 * __expf(e0 - m) : 0.f;
        float p1 = c1 > 0.f ? c1 * __expf(e1 - m) : 0.f;
        float sum = p0 + p1;
        #pragma unroll
        for (int o = 32; o; o >>= 1) sum += __shfl_xor(sum, o);
        float inv = 1.f / sum;
        alpha[(size_t)z * 16384 + d * 128 + lane]      = f2bf(p0 * inv);
        alpha[(size_t)z * 16384 + d * 128 + 64 + lane] = f2bf(p1 * inv);
    }
}

// ---------------- time mix: out = gelu(W_time @ y + b_time) + y, in-place on d_out ----------------
__global__ __launch_bounds__(256) void timemix_kernel(float* __restrict__ y,
                                                      const float* __restrict__ Wt,
                                                      const float* __restrict__ bt) {
    __shared__ float w[1024];
    __shared__ float bts[32];
    int tid = threadIdx.x;
    for (int i = tid; i < 1024; i += 256) w[i] = Wt[i];
    if (tid < 32) bts[tid] = bt[tid];
    __syncthreads();
    int blk = blockIdx.x;               // 2048 blocks
    int b = blk >> 8;                   // 8
    int rem = blk & 255;
    int n = rem >> 1;                   // 128
    int f = (rem & 1) * 256 + tid;      // 512
    size_t base = ((size_t)b * 4096 + n) * 512 + f;   // (b,0,n,f); s-stride = 65536
    float ys[32];
    #pragma unroll
    for (int s = 0; s < 32; ++s) ys[s] = y[base + (size_t)s * 65536];
    #pragma unroll
    for (int t = 0; t < 32; ++t) {
        float a = bts[t];
        #pragma unroll
        for (int s = 0; s < 32; ++s) a += w[t * 32 + s] * ys[s];
        y[base + (size_t)t * 65536] = gelu_f(a) + ys[t];
    }
}

extern "C" void kernel_launch(void* const* d_in, const int* in_sizes, int n_in,
                              void* d_out, int out_size, void* d_ws, size_t ws_size,
                              hipStream_t stream) {
    const float* x     = (const float*)d_in[0];
    const int*   ei    = (const int*)d_in[1];
    const int*   valid = (const int*)d_in[2];
    const float* W1    = (const float*)d_in[3];
    const float* a1s   = (const float*)d_in[4];
    const float* a1d   = (const float*)d_in[5];
    const float* b1    = (const float*)d_in[6];
    const float* W2    = (const float*)d_in[7];
    const float* a2s   = (const float*)d_in[8];
    const float* a2d   = (const float*)d_in[9];
    const float* b2    = (const float*)d_in[10];
    const float* Wt    = (const float*)d_in[11];
    const float* bt    = (const float*)d_in[12];
    float* out = (float*)d_out;

    char* ws = (char*)d_ws;
    u16* Xb   = (u16*)(ws);                       // 33,554,432 B (layer input, reused)
    u16* HTb  = (u16*)(ws + 33554432);            // 33,554,432 B (H^T, reused)
    u16* ALPH = (u16*)(ws + 67108864);            //  8,388,608 B
    u16* W1b  = (u16*)(ws + 75497472);            //    524,288 B
    u16* W2b  = (u16*)(ws + 76021760);            //    524,288 B
    float* SS = (float*)(ws + 76546048);          //    131,072 B
    float* SD = (float*)(ws + 76677120);          //    131,072 B

    // convert inputs to bf16
    cvt_kernel<<<2048, 256, 0, stream>>>(x, Xb, 16777216 / 4);
    cvt_kernel<<<128, 256, 0, stream>>>(W1, W1b, 262144 / 4);
    cvt_kernel<<<128, 256, 0, stream>>>(W2, W2b, 262144 / 4);

    // ---- layer 1 ----
    gemm_nt<512, 0><<<dim3(256, 4, 1), 256, 0, stream>>>(Xb, W1b, 0, 0, HTb, nullptr, nullptr, nullptr);
    scores_kernel<<<256, 256, 0, stream>>>(HTb, a1s, a1d, SS, SD);
    alpha_kernel<<<256, 256, 0, stream>>>(ei, SS, SD, ALPH);
    gemm_nt<128, 1><<<dim3(1, 4, 256), 256, 0, stream>>>(ALPH, HTb, 16384, 65536, Xb, nullptr, b1, nullptr);

    // ---- layer 2 ----
    gemm_nt<512, 0><<<dim3(256, 4, 1), 256, 0, stream>>>(Xb, W2b, 0, 0, HTb, nullptr, nullptr, nullptr);
    scores_kernel<<<256, 256, 0, stream>>>(HTb, a2s, a2d, SS, SD);
    alpha_kernel<<<256, 256, 0, stream>>>(ei, SS, SD, ALPH);
    gemm_nt<128, 2><<<dim3(1, 4, 256), 256, 0, stream>>>(ALPH, HTb, 16384, 65536, nullptr, out, b2, valid);

    // ---- time mixing (in-place on d_out) ----
    timemix_kernel<<<2048, 256, 0, stream>>>(out, Wt, bt);
}

// Round 2
// 274.573 us; speedup vs baseline: 1.2585x; 1.2585x over previous
//
#include <hip/hip_runtime.h>

using u16 = unsigned short;
using u32 = unsigned int;

typedef __bf16 bf16x8 __attribute__((ext_vector_type(8)));
typedef float  f32x4  __attribute__((ext_vector_type(4)));

__device__ __forceinline__ u16 f2bf(float f) {
    u32 u = __float_as_uint(f);
    u32 r = u + 0x7fffu + ((u >> 16) & 1u);
    return (u16)(r >> 16);
}
__device__ __forceinline__ float bf2f(u16 u) {
    return __uint_as_float(((u32)u) << 16);
}
__device__ __forceinline__ float gelu_f(float x) {
    return 0.5f * x * (1.0f + erff(x * 0.70710678118654752440f));
}

// ---------------- f32 -> bf16 conversion ----------------
__global__ __launch_bounds__(256) void cvt_kernel(const float* __restrict__ in,
                                                  u16* __restrict__ out, int n4) {
    int i = blockIdx.x * 256 + threadIdx.x;
    int stride = gridDim.x * 256;
    for (; i < n4; i += stride) {
        float4 v = ((const float4*)in)[i];
        ushort4 o;
        o.x = f2bf(v.x); o.y = f2bf(v.y); o.z = f2bf(v.z); o.w = f2bf(v.w);
        ((ushort4*)out)[i] = o;
    }
}

// ---------------- zero SS/SD ----------------
__global__ __launch_bounds__(256) void zero_kernel(float* __restrict__ p, int n4) {
    int i = blockIdx.x * 256 + threadIdx.x;
    if (i < n4) ((float4*)p)[i] = make_float4(0.f, 0.f, 0.f, 0.f);
}

// ---------------- NT GEMM: C[m][n] = sum_k A[m][k]*B[n][k] ----------------
// MODE 0: write bf16 H^T per graph: HT[graph][n][node]   (graph = tm>>7, node = local row)
// MODE 1: write bf16 gelu(C + bias[n]) row-major [m][n]  (AGG1 -> next layer input)
// MODE 2: write f32 (C + bias[n]) * timemask row-major into d_out (AGG2)
template<int KTOT, int MODE>
__global__ __launch_bounds__(256) void gemm_nt(
    const u16* __restrict__ A, const u16* __restrict__ B,
    long aBatch, long bBatch,
    u16* __restrict__ outU, float* __restrict__ outF,
    const float* __restrict__ bias, const int* __restrict__ valid)
{
    constexpr int LS = 40;  // LDS row stride (32 + 8 pad) in bf16 elems
    __shared__ __align__(16) u16 As[128 * LS];
    __shared__ __align__(16) u16 Bs[128 * LS];

    const int tid  = threadIdx.x;
    const int lane = tid & 63;
    const int w    = tid >> 6;
    const int wm   = w & 1, wn = w >> 1;
    const int z    = blockIdx.z;
    const int tm   = blockIdx.x * 128;
    const int tn   = blockIdx.y * 128;

    const u16* Ag = A + (size_t)z * aBatch + (size_t)tm * KTOT;
    const u16* Bg = B + (size_t)z * bBatch + (size_t)tn * KTOT;

    const int r0 = tid >> 2;          // staging row (0..63), second chunk row+64
    const int kc = (tid & 3) * 8;     // staging k offset (elems)
    const int fr = lane & 15;         // fragment row (A) / col (B)
    const int ko = (lane >> 4) * 8;   // fragment k offset

    f32x4 acc[4][4] = {};

    for (int k0 = 0; k0 < KTOT; k0 += 32) {
        *(uint4*)&As[(r0     ) * LS + kc] = *(const uint4*)&Ag[(size_t)(r0     ) * KTOT + k0 + kc];
        *(uint4*)&As[(r0 + 64) * LS + kc] = *(const uint4*)&Ag[(size_t)(r0 + 64) * KTOT + k0 + kc];
        *(uint4*)&Bs[(r0     ) * LS + kc] = *(const uint4*)&Bg[(size_t)(r0     ) * KTOT + k0 + kc];
        *(uint4*)&Bs[(r0 + 64) * LS + kc] = *(const uint4*)&Bg[(size_t)(r0 + 64) * KTOT + k0 + kc];
        __syncthreads();
        bf16x8 af[4], bf_[4];
        #pragma unroll
        for (int i = 0; i < 4; ++i) {
            af[i]  = *(const bf16x8*)&As[(wm * 64 + i * 16 + fr) * LS + ko];
            bf_[i] = *(const bf16x8*)&Bs[(wn * 64 + i * 16 + fr) * LS + ko];
        }
        #pragma unroll
        for (int i = 0; i < 4; ++i)
            #pragma unroll
            for (int j = 0; j < 4; ++j)
                acc[i][j] = __builtin_amdgcn_mfma_f32_16x16x32_bf16(af[i], bf_[j], acc[i][j], 0, 0, 0);
        __syncthreads();
    }

    const int crow = (lane >> 4) * 4;
    const int ccol = lane & 15;

    if (MODE == 0) {
        u16* H = outU + (size_t)(tm >> 7) * (512 * 128);
        #pragma unroll
        for (int i = 0; i < 4; ++i) {
            int node0 = wm * 64 + i * 16 + crow;
            #pragma unroll
            for (int j = 0; j < 4; ++j) {
                int n = tn + wn * 64 + j * 16 + ccol;
                ushort4 o;
                o.x = f2bf(acc[i][j][0]);
                o.y = f2bf(acc[i][j][1]);
                o.z = f2bf(acc[i][j][2]);
                o.w = f2bf(acc[i][j][3]);
                *(ushort4*)&H[(size_t)n * 128 + node0] = o;
            }
        }
    } else if (MODE == 1) {
        #pragma unroll
        for (int i = 0; i < 4; ++i) {
            int m0 = z * 128 + wm * 64 + i * 16 + crow;
            #pragma unroll
            for (int j = 0; j < 4; ++j) {
                int n = tn + wn * 64 + j * 16 + ccol;
                float bv = bias[n];
                #pragma unroll
                for (int jj = 0; jj < 4; ++jj) {
                    float v = gelu_f(acc[i][j][jj] + bv);
                    outU[(size_t)(m0 + jj) * 512 + n] = f2bf(v);
                }
            }
        }
    } else {
        int b = z >> 5, t = z & 31;
        float msk = (t < valid[b]) ? 1.0f : 0.0f;
        #pragma unroll
        for (int i = 0; i < 4; ++i) {
            int m0 = z * 128 + wm * 64 + i * 16 + crow;
            #pragma unroll
            for (int j = 0; j < 4; ++j) {
                int n = tn + wn * 64 + j * 16 + ccol;
                float bv = bias[n];
                #pragma unroll
                for (int jj = 0; jj < 4; ++jj) {
                    outF[(size_t)(m0 + jj) * 512 + n] = (acc[i][j][jj] + bv) * msk;
                }
            }
        }
    }
}

// ---------------- per-node attention scores from bf16 H^T (vectorized) ----------------
// ss[g*128+node] += sum_f HT[g][f][node] * a_s[f]   (f-quarter per block, global atomic)
__global__ __launch_bounds__(256) void scores2_kernel(const u16* __restrict__ HT,
                                                      const float* __restrict__ a_s,
                                                      const float* __restrict__ a_d,
                                                      float* __restrict__ ss,
                                                      float* __restrict__ sd) {
    __shared__ float sA[128], dA[128];
    const int blk = blockIdx.x;
    const int g = blk >> 2, q = blk & 3;          // graph, f-quarter
    const int tid = threadIdx.x;
    const int fo = tid >> 4;                       // 0..15
    const int node8 = (tid & 15) * 8;              // 0,8,...,120

    if (tid < 128) { sA[tid] = 0.f; dA[tid] = 0.f; }
    __syncthreads();

    const u16* H = HT + (size_t)g * 65536;
    float as_[8] = {}, ad_[8] = {};
    #pragma unroll
    for (int it = 0; it < 8; ++it) {
        int f = q * 128 + fo + it * 16;
        uint4 v = *(const uint4*)&H[(size_t)f * 128 + node8];
        float cs = a_s[f], cd = a_d[f];
        const u16* e = (const u16*)&v;
        #pragma unroll
        for (int k = 0; k < 8; ++k) {
            float h = bf2f(e[k]);
            as_[k] += h * cs;
            ad_[k] += h * cd;
        }
    }
    #pragma unroll
    for (int k = 0; k < 8; ++k) {
        atomicAdd(&sA[node8 + k], as_[k]);
        atomicAdd(&dA[node8 + k], ad_[k]);
    }
    __syncthreads();
    if (tid < 128) {
        atomicAdd(&ss[g * 128 + tid], sA[tid]);
        atomicAdd(&sd[g * 128 + tid], dA[tid]);
    }
}

// ---------------- dense per-graph softmax -> bf16 alpha[dst][src] ----------------
__global__ __launch_bounds__(256) void alpha_kernel(const int* __restrict__ ei,
                                                    const float* __restrict__ ss,
                                                    const float* __restrict__ sd,
                                                    u16* __restrict__ alpha) {
    __shared__ float cnt[128 * 128];   // 64 KB
    __shared__ float s_s[128], s_d[128];
    int z = blockIdx.x, tid = threadIdx.x;
    for (int i = tid; i < 16384; i += 256) cnt[i] = 0.f;
    if (tid < 128) {
        s_s[tid] = ss[z * 128 + tid];
        s_d[tid] = sd[z * 128 + tid];
    }
    __syncthreads();
    const int* e = ei + (size_t)z * 4096;
    for (int i = tid; i < 2048; i += 256) {
        int s = e[i], d = e[2048 + i];
        atomicAdd(&cnt[d * 128 + s], 1.0f);
    }
    if (tid < 128) atomicAdd(&cnt[tid * 128 + tid], 1.0f);  // self loop
    __syncthreads();
    int lane = tid & 63, wv = tid >> 6;
    for (int d = wv; d < 128; d += 4) {
        float sdv = s_d[d];
        float c0 = cnt[d * 128 + lane], c1 = cnt[d * 128 + 64 + lane];
        float e0 = s_s[lane] + sdv;       e0 = e0 > 0.f ? e0 : 0.2f * e0;
        float e1 = s_s[64 + lane] + sdv;  e1 = e1 > 0.f ? e1 : 0.2f * e1;
        float m = fmaxf(c0 > 0.f ? e0 : -1e30f, c1 > 0.f ? e1 : -1e30f);
        #pragma unroll
        for (int o = 32; o; o >>= 1) m = fmaxf(m, __shfl_xor(m, o));
        float p0 = c0 > 0.f ? c0 * __expf(e0 - m) : 0.f;
        float p1 = c1 > 0.f ? c1 * __expf(e1 - m) : 0.f;
        float sum = p0 + p1;
        #pragma unroll
        for (int o = 32; o; o >>= 1) sum += __shfl_xor(sum, o);
        float inv = 1.f / sum;
        alpha[(size_t)z * 16384 + d * 128 + lane]      = f2bf(p0 * inv);
        alpha[(size_t)z * 16384 + d * 128 + 64 + lane] = f2bf(p1 * inv);
    }
}

// ---------------- time mix: out = gelu(W_time @ y + b_time) + y, in-place on d_out ----------------
__global__ __launch_bounds__(256) void timemix_kernel(float* __restrict__ y,
                                                      const float* __restrict__ Wt,
                                                      const float* __restrict__ bt) {
    __shared__ float w[1024];
    __shared__ float bts[32];
    int tid = threadIdx.x;
    for (int i = tid; i < 1024; i += 256) w[i] = Wt[i];
    if (tid < 32) bts[tid] = bt[tid];
    __syncthreads();
    int blk = blockIdx.x;               // 2048 blocks
    int b = blk >> 8;                   // 8
    int rem = blk & 255;
    int n = rem >> 1;                   // 128
    int f = (rem & 1) * 256 + tid;      // 512
    size_t base = ((size_t)b * 4096 + n) * 512 + f;   // (b,0,n,f); s-stride = 65536
    float ys[32];
    #pragma unroll
    for (int s = 0; s < 32; ++s) ys[s] = y[base + (size_t)s * 65536];
    #pragma unroll
    for (int t = 0; t < 32; ++t) {
        float a = bts[t];
        #pragma unroll
        for (int s = 0; s < 32; ++s) a += w[t * 32 + s] * ys[s];
        y[base + (size_t)t * 65536] = gelu_f(a) + ys[t];
    }
}

extern "C" void kernel_launch(void* const* d_in, const int* in_sizes, int n_in,
                              void* d_out, int out_size, void* d_ws, size_t ws_size,
                              hipStream_t stream) {
    const float* x     = (const float*)d_in[0];
    const int*   ei    = (const int*)d_in[1];
    const int*   valid = (const int*)d_in[2];
    const float* W1    = (const float*)d_in[3];
    const float* a1s   = (const float*)d_in[4];
    const float* a1d   = (const float*)d_in[5];
    const float* b1    = (const float*)d_in[6];
    const float* W2    = (const float*)d_in[7];
    const float* a2s   = (const float*)d_in[8];
    const float* a2d   = (const float*)d_in[9];
    const float* b2    = (const float*)d_in[10];
    const float* Wt    = (const float*)d_in[11];
    const float* bt    = (const float*)d_in[12];
    float* out = (float*)d_out;

    char* ws = (char*)d_ws;
    u16* Xb   = (u16*)(ws);                       // 33,554,432 B (layer input, reused)
    u16* HTb  = (u16*)(ws + 33554432);            // 33,554,432 B (H^T, reused)
    u16* ALPH = (u16*)(ws + 67108864);            //  8,388,608 B
    u16* W1b  = (u16*)(ws + 75497472);            //    524,288 B
    u16* W2b  = (u16*)(ws + 76021760);            //    524,288 B
    float* SS = (float*)(ws + 76546048);          //    131,072 B
    float* SD = (float*)(ws + 76677120);          //    131,072 B

    // convert inputs to bf16
    cvt_kernel<<<2048, 256, 0, stream>>>(x, Xb, 16777216 / 4);
    cvt_kernel<<<128, 256, 0, stream>>>(W1, W1b, 262144 / 4);
    cvt_kernel<<<128, 256, 0, stream>>>(W2, W2b, 262144 / 4);

    // ---- layer 1 ----
    gemm_nt<512, 0><<<dim3(256, 4, 1), 256, 0, stream>>>(Xb, W1b, 0, 0, HTb, nullptr, nullptr, nullptr);
    zero_kernel<<<64, 256, 0, stream>>>(SS, 16384);   // zeroes SS and SD (contiguous 2*32768 floats)
    scores2_kernel<<<1024, 256, 0, stream>>>(HTb, a1s, a1d, SS, SD);
    alpha_kernel<<<256, 256, 0, stream>>>(ei, SS, SD, ALPH);
    gemm_nt<128, 1><<<dim3(1, 4, 256), 256, 0, stream>>>(ALPH, HTb, 16384, 65536, Xb, nullptr, b1, nullptr);

    // ---- layer 2 ----
    gemm_nt<512, 0><<<dim3(256, 4, 1), 256, 0, stream>>>(Xb, W2b, 0, 0, HTb, nullptr, nullptr, nullptr);
    zero_kernel<<<64, 256, 0, stream>>>(SS, 16384);
    scores2_kernel<<<1024, 256, 0, stream>>>(HTb, a2s, a2d, SS, SD);
    alpha_kernel<<<256, 256, 0, stream>>>(ei, SS, SD, ALPH);
    gemm_nt<128, 2><<<dim3(1, 4, 256), 256, 0, stream>>>(ALPH, HTb, 16384, 65536, nullptr, out, b2, valid);

    // ---- time mixing (in-place on d_out) ----
    timemix_kernel<<<2048, 256, 0, stream>>>(out, Wt, bt);
}

// Round 3
// 220.940 us; speedup vs baseline: 1.5640x; 1.2427x over previous
//
#include <hip/hip_runtime.h>

using u16 = unsigned short;
using u32 = unsigned int;

typedef __bf16 bf16x8 __attribute__((ext_vector_type(8)));
typedef float  f32x4  __attribute__((ext_vector_type(4)));

__device__ __forceinline__ u16 f2bf(float f) {
    u32 u = __float_as_uint(f);
    u32 r = u + 0x7fffu + ((u >> 16) & 1u);
    return (u16)(r >> 16);
}
__device__ __forceinline__ float bf2f(u16 u) {
    return __uint_as_float(((u32)u) << 16);
}
__device__ __forceinline__ float gelu_f(float x) {
    return 0.5f * x * (1.0f + erff(x * 0.70710678118654752440f));
}

// async global->LDS, 16B per lane; LDS dest = wave-uniform base + lane*16
#define GLOAD16(gp, lp) __builtin_amdgcn_global_load_lds( \
    (const __attribute__((address_space(1))) void*)(gp),  \
    (__attribute__((address_space(3))) void*)(lp), 16, 0, 0)

// ---------------- prep: cvt x/W1/W2 to bf16 + zero score buffers ----------------
__global__ __launch_bounds__(256) void prep_kernel(
    const float* __restrict__ x, const float* __restrict__ W1, const float* __restrict__ W2,
    u16* __restrict__ Xb, u16* __restrict__ W1b, u16* __restrict__ W2b,
    float* __restrict__ Z)   // Z = SS1/SD1/SS2/SD2 contiguous, 4*32768 floats
{
    const int i0 = blockIdx.x * 256 + threadIdx.x;
    const int stride = gridDim.x * 256;
    for (int i = i0; i < 32768; i += stride)
        ((float4*)Z)[i] = make_float4(0.f, 0.f, 0.f, 0.f);
    for (int i = i0; i < 65536; i += stride) {
        float4 v = ((const float4*)W1)[i];
        ushort4 o; o.x = f2bf(v.x); o.y = f2bf(v.y); o.z = f2bf(v.z); o.w = f2bf(v.w);
        ((ushort4*)W1b)[i] = o;
    }
    for (int i = i0; i < 65536; i += stride) {
        float4 v = ((const float4*)W2)[i];
        ushort4 o; o.x = f2bf(v.x); o.y = f2bf(v.y); o.z = f2bf(v.z); o.w = f2bf(v.w);
        ((ushort4*)W2b)[i] = o;
    }
    for (int i = i0; i < 4194304; i += stride) {
        float4 v = ((const float4*)x)[i];
        ushort4 o; o.x = f2bf(v.x); o.y = f2bf(v.y); o.z = f2bf(v.z); o.w = f2bf(v.w);
        ((ushort4*)Xb)[i] = o;
    }
}

// ---------------- NT GEMM: C[m][n] = sum_k A[m][k]*B[n][k] ----------------
// m97 structure: global_load_lds width-16 into linear [128][32] LDS tiles.
// MODE 0: write bf16 H^T per graph (g=blockIdx.x): HT[g][n][node]; fused scores -> ss/sd
// MODE 1: write bf16 gelu(C + bias[n]) row-major [m][n]
// MODE 2: write f32 (C + bias[n]) * timemask row-major
template<int KTOT, int MODE>
__global__ __launch_bounds__(256) void gemm_nt(
    const u16* __restrict__ A, const u16* __restrict__ B,
    long aBatch, long bBatch,
    u16* __restrict__ outU, float* __restrict__ outF,
    const float* __restrict__ bias, const int* __restrict__ valid,
    const float* __restrict__ a_s, const float* __restrict__ a_d,
    float* __restrict__ ss, float* __restrict__ sd)
{
    __shared__ __align__(16) u16 As[128 * 32];
    __shared__ __align__(16) u16 Bs[128 * 32];
    __shared__ float sred[(MODE == 0) ? 128 * 33 : 4];  // padded stride-33 scatter buf

    const int tid  = threadIdx.x;
    const int lane = tid & 63;
    const int w    = tid >> 6;      // wave 0..3
    const int wm   = w & 1, wn = w >> 1;
    const int z    = blockIdx.z;
    const int tm   = blockIdx.x * 128;
    const int tn   = blockIdx.y * 128;
    const int g    = blockIdx.x;    // graph id in MODE 0 (128 rows == 1 graph)

    const u16* Ag = A + (size_t)z * aBatch + (size_t)tm * KTOT;
    const u16* Bg = B + (size_t)z * bBatch + (size_t)tn * KTOT;

    // staging geometry: wave w issue q covers rows (w*2+q)*16 + (lane>>2), k elems (lane&3)*8
    const int srow = lane >> 2;
    const int skel = (lane & 3) * 8;
    const u16* Ag0 = Ag + (size_t)(w * 32 + srow) * KTOT + skel;
    const u16* Bg0 = Bg + (size_t)(w * 32 + srow) * KTOT + skel;
    u16* Asl = &As[w * 1024];       // wave-uniform LDS base (elems)
    u16* Bsl = &Bs[w * 1024];

    const int fr = lane & 15;       // fragment row (A) / col (B)
    const int ko = (lane >> 4) * 8; // fragment k offset (elems)

    f32x4 acc[4][4] = {};

    for (int k0 = 0; k0 < KTOT; k0 += 32) {
        GLOAD16(Ag0 + k0,             Asl);
        GLOAD16(Ag0 + k0 + 16 * KTOT, Asl + 512);
        GLOAD16(Bg0 + k0,             Bsl);
        GLOAD16(Bg0 + k0 + 16 * KTOT, Bsl + 512);
        __syncthreads();
        bf16x8 af[4], bf_[4];
        #pragma unroll
        for (int i = 0; i < 4; ++i) {
            af[i]  = *(const bf16x8*)&As[(wm * 64 + i * 16 + fr) * 32 + ko];
            bf_[i] = *(const bf16x8*)&Bs[(wn * 64 + i * 16 + fr) * 32 + ko];
        }
        #pragma unroll
        for (int i = 0; i < 4; ++i)
            #pragma unroll
            for (int j = 0; j < 4; ++j)
                acc[i][j] = __builtin_amdgcn_mfma_f32_16x16x32_bf16(af[i], bf_[j], acc[i][j], 0, 0, 0);
        __syncthreads();
    }

    const int crow = (lane >> 4) * 4;
    const int ccol = lane & 15;

    if (MODE == 0) {
        // H^T write: HT[g][n][node]
        u16* H = outU + (size_t)g * (512 * 128);
        #pragma unroll
        for (int i = 0; i < 4; ++i) {
            int node0 = wm * 64 + i * 16 + crow;
            #pragma unroll
            for (int j = 0; j < 4; ++j) {
                int n = tn + wn * 64 + j * 16 + ccol;
                ushort4 o;
                o.x = f2bf(acc[i][j][0]);
                o.y = f2bf(acc[i][j][1]);
                o.z = f2bf(acc[i][j][2]);
                o.w = f2bf(acc[i][j][3]);
                *(ushort4*)&H[(size_t)n * 128 + node0] = o;
            }
        }
        // ---- fused attention scores: ss[g][node] += h[node] . a_s (this block's 128 f) ----
        float fsv[4], fdv[4];
        #pragma unroll
        for (int j = 0; j < 4; ++j) {
            int f = tn + wn * 64 + j * 16 + ccol;
            fsv[j] = a_s[f]; fdv[j] = a_d[f];
        }
        float ps[16], pd[16];
        #pragma unroll
        for (int i = 0; i < 4; ++i)
            #pragma unroll
            for (int jj = 0; jj < 4; ++jj) {
                float s = 0.f, d = 0.f;
                #pragma unroll
                for (int j = 0; j < 4; ++j) {
                    s += acc[i][j][jj] * fsv[j];
                    d += acc[i][j][jj] * fdv[j];
                }
                ps[i * 4 + jj] = s; pd[i * 4 + jj] = d;
            }
        // bijective scatter: slot (node, wn*16+ccol), stride 33 (conflict-free row read)
        #pragma unroll
        for (int i = 0; i < 4; ++i)
            #pragma unroll
            for (int jj = 0; jj < 4; ++jj)
                sred[(wm * 64 + i * 16 + crow + jj) * 33 + wn * 16 + ccol] = ps[i * 4 + jj];
        __syncthreads();
        if (tid < 128) {
            float s = 0.f;
            const float* r = &sred[tid * 33];
            #pragma unroll
            for (int c = 0; c < 32; ++c) s += r[c];
            atomicAdd(&ss[g * 128 + tid], s);
        }
        __syncthreads();
        #pragma unroll
        for (int i = 0; i < 4; ++i)
            #pragma unroll
            for (int jj = 0; jj < 4; ++jj)
                sred[(wm * 64 + i * 16 + crow + jj) * 33 + wn * 16 + ccol] = pd[i * 4 + jj];
        __syncthreads();
        if (tid < 128) {
            float s = 0.f;
            const float* r = &sred[tid * 33];
            #pragma unroll
            for (int c = 0; c < 32; ++c) s += r[c];
            atomicAdd(&sd[g * 128 + tid], s);
        }
    } else if (MODE == 1) {
        #pragma unroll
        for (int i = 0; i < 4; ++i) {
            int m0 = z * 128 + wm * 64 + i * 16 + crow;
            #pragma unroll
            for (int j = 0; j < 4; ++j) {
                int n = tn + wn * 64 + j * 16 + ccol;
                float bv = bias[n];
                #pragma unroll
                for (int jj = 0; jj < 4; ++jj) {
                    float v = gelu_f(acc[i][j][jj] + bv);
                    outU[(size_t)(m0 + jj) * 512 + n] = f2bf(v);
                }
            }
        }
    } else {
        int b = z >> 5, t = z & 31;
        float msk = (t < valid[b]) ? 1.0f : 0.0f;
        #pragma unroll
        for (int i = 0; i < 4; ++i) {
            int m0 = z * 128 + wm * 64 + i * 16 + crow;
            #pragma unroll
            for (int j = 0; j < 4; ++j) {
                int n = tn + wn * 64 + j * 16 + ccol;
                float bv = bias[n];
                #pragma unroll
                for (int jj = 0; jj < 4; ++jj) {
                    outF[(size_t)(m0 + jj) * 512 + n] = (acc[i][j][jj] + bv) * msk;
                }
            }
        }
    }
}

// ---------------- dense per-graph softmax -> bf16 alpha[dst][src] ----------------
__global__ __launch_bounds__(256) void alpha_kernel(const int* __restrict__ ei,
                                                    const float* __restrict__ ss,
                                                    const float* __restrict__ sd,
                                                    u16* __restrict__ alpha) {
    __shared__ float cnt[128 * 128];   // 64 KB
    __shared__ float s_s[128], s_d[128];
    int z = blockIdx.x, tid = threadIdx.x;
    for (int i = tid; i < 4096; i += 256)
        ((float4*)cnt)[i] = make_float4(0.f, 0.f, 0.f, 0.f);
    if (tid < 128) {
        s_s[tid] = ss[z * 128 + tid];
        s_d[tid] = sd[z * 128 + tid];
    }
    __syncthreads();
    const int4* es = (const int4*)(ei + (size_t)z * 4096);
    for (int i = tid; i < 512; i += 256) {
        int4 s4 = es[i];
        int4 d4 = es[512 + i];
        atomicAdd(&cnt[d4.x * 128 + s4.x], 1.0f);
        atomicAdd(&cnt[d4.y * 128 + s4.y], 1.0f);
        atomicAdd(&cnt[d4.z * 128 + s4.z], 1.0f);
        atomicAdd(&cnt[d4.w * 128 + s4.w], 1.0f);
    }
    if (tid < 128) atomicAdd(&cnt[tid * 128 + tid], 1.0f);  // self loop
    __syncthreads();
    int lane = tid & 63, wv = tid >> 6;
    for (int d = wv; d < 128; d += 4) {
        float sdv = s_d[d];
        float c0 = cnt[d * 128 + lane], c1 = cnt[d * 128 + 64 + lane];
        float e0 = s_s[lane] + sdv;       e0 = e0 > 0.f ? e0 : 0.2f * e0;
        float e1 = s_s[64 + lane] + sdv;  e1 = e1 > 0.f ? e1 : 0.2f * e1;
        float m = fmaxf(c0 > 0.f ? e0 : -1e30f, c1 > 0.f ? e1 : -1e30f);
        #pragma unroll
        for (int o = 32; o; o >>= 1) m = fmaxf(m, __shfl_xor(m, o));
        float p0 = c0 > 0.f ? c0 * __expf(e0 - m) : 0.f;
        float p1 = c1 > 0.f ? c1 * __expf(e1 - m) : 0.f;
        float sum = p0 + p1;
        #pragma unroll
        for (int o = 32; o; o >>= 1) sum += __shfl_xor(sum, o);
        float inv = 1.f / sum;
        alpha[(size_t)z * 16384 + d * 128 + lane]      = f2bf(p0 * inv);
        alpha[(size_t)z * 16384 + d * 128 + 64 + lane] = f2bf(p1 * inv);
    }
}

// ---------------- time mix: out = gelu(W_time @ y + b_time) + y, in-place ----------------
__global__ __launch_bounds__(256) void timemix_kernel(float* __restrict__ y,
                                                      const float* __restrict__ Wt,
                                                      const float* __restrict__ bt) {
    __shared__ float wsm[1024];
    __shared__ float bts[32];
    int tid = threadIdx.x;
    for (int i = tid; i < 1024; i += 256) wsm[i] = Wt[i];
    if (tid < 32) bts[tid] = bt[tid];
    __syncthreads();
    int blk = blockIdx.x;               // 2048 blocks
    int b = blk >> 8;
    int rem = blk & 255;
    int n = rem >> 1;
    int f = (rem & 1) * 256 + tid;
    size_t base = ((size_t)b * 4096 + n) * 512 + f;   // (b,0,n,f); s-stride = 65536
    float ys[32];
    #pragma unroll
    for (int s = 0; s < 32; ++s) ys[s] = y[base + (size_t)s * 65536];
    #pragma unroll
    for (int t = 0; t < 32; ++t) {
        float a = bts[t];
        #pragma unroll
        for (int s = 0; s < 32; ++s) a += wsm[t * 32 + s] * ys[s];
        y[base + (size_t)t * 65536] = gelu_f(a) + ys[t];
    }
}

extern "C" void kernel_launch(void* const* d_in, const int* in_sizes, int n_in,
                              void* d_out, int out_size, void* d_ws, size_t ws_size,
                              hipStream_t stream) {
    const float* x     = (const float*)d_in[0];
    const int*   ei    = (const int*)d_in[1];
    const int*   valid = (const int*)d_in[2];
    const float* W1    = (const float*)d_in[3];
    const float* a1s   = (const float*)d_in[4];
    const float* a1d   = (const float*)d_in[5];
    const float* b1    = (const float*)d_in[6];
    const float* W2    = (const float*)d_in[7];
    const float* a2s   = (const float*)d_in[8];
    const float* a2d   = (const float*)d_in[9];
    const float* b2    = (const float*)d_in[10];
    const float* Wt    = (const float*)d_in[11];
    const float* bt    = (const float*)d_in[12];
    float* out = (float*)d_out;

    char* ws = (char*)d_ws;
    u16* Xb   = (u16*)(ws);                       // 33,554,432 B
    u16* HTb  = (u16*)(ws + 33554432);            // 33,554,432 B
    u16* ALPH = (u16*)(ws + 67108864);            //  8,388,608 B
    u16* W1b  = (u16*)(ws + 75497472);            //    524,288 B
    u16* W2b  = (u16*)(ws + 76021760);            //    524,288 B
    float* SS1 = (float*)(ws + 76546048);         //    131,072 B  (zeroed by prep)
    float* SD1 = (float*)(ws + 76677120);         //    131,072 B
    float* SS2 = (float*)(ws + 76808192);         //    131,072 B
    float* SD2 = (float*)(ws + 76939264);         //    131,072 B

    prep_kernel<<<2048, 256, 0, stream>>>(x, W1, W2, Xb, W1b, W2b, SS1);

    // ---- layer 1 ----
    gemm_nt<512, 0><<<dim3(256, 4, 1), 256, 0, stream>>>(Xb, W1b, 0, 0, HTb, nullptr,
        nullptr, nullptr, a1s, a1d, SS1, SD1);
    alpha_kernel<<<256, 256, 0, stream>>>(ei, SS1, SD1, ALPH);
    gemm_nt<128, 1><<<dim3(1, 4, 256), 256, 0, stream>>>(ALPH, HTb, 16384, 65536, Xb, nullptr,
        b1, nullptr, nullptr, nullptr, nullptr, nullptr);

    // ---- layer 2 ----
    gemm_nt<512, 0><<<dim3(256, 4, 1), 256, 0, stream>>>(Xb, W2b, 0, 0, HTb, nullptr,
        nullptr, nullptr, a2s, a2d, SS2, SD2);
    alpha_kernel<<<256, 256, 0, stream>>>(ei, SS2, SD2, ALPH);
    gemm_nt<128, 2><<<dim3(1, 4, 256), 256, 0, stream>>>(ALPH, HTb, 16384, 65536, nullptr, out,
        b2, valid, nullptr, nullptr, nullptr, nullptr);

    // ---- time mixing (in-place on d_out) ----
    timemix_kernel<<<2048, 256, 0, stream>>>(out, Wt, bt);
}

// Round 5
// 216.650 us; speedup vs baseline: 1.5950x; 1.0198x over previous
//
#include <hip/hip_runtime.h>

using u16 = unsigned short;
using u32 = unsigned int;

typedef __bf16 bf16x8 __attribute__((ext_vector_type(8)));
typedef float  f32x4  __attribute__((ext_vector_type(4)));

__device__ __forceinline__ u16 f2bf(float f) {
    u32 u = __float_as_uint(f);
    u32 r = u + 0x7fffu + ((u >> 16) & 1u);
    return (u16)(r >> 16);
}
__device__ __forceinline__ float bf2f(u16 u) {
    return __uint_as_float(((u32)u) << 16);
}
__device__ __forceinline__ float gelu_f(float x) {
    return 0.5f * x * (1.0f + erff(x * 0.70710678118654752440f));
}

// async global->LDS, 16B per lane; LDS dest = wave-uniform base + lane*16,
// global source is PER-LANE (pre-swizzled source pattern).
#define GLOAD16(gp, lp) __builtin_amdgcn_global_load_lds( \
    (const __attribute__((address_space(1))) void*)(gp),  \
    (__attribute__((address_space(3))) void*)(lp), 16, 0, 0)

#define WAITV(n) asm volatile("s_waitcnt vmcnt(" #n ")" ::: "memory")
#define WAITL0   asm volatile("s_waitcnt lgkmcnt(0)" ::: "memory")
#define BARRIER  __builtin_amdgcn_s_barrier()

// ---------------- prep: cvt W1/W2 to bf16 + zero score buffers ----------------
__global__ __launch_bounds__(256) void prep_kernel(
    const float* __restrict__ W1, const float* __restrict__ W2,
    u16* __restrict__ W1b, u16* __restrict__ W2b,
    float* __restrict__ Z)   // Z = SS1/SD1/SS2/SD2 contiguous, 4*32768 floats
{
    const int i0 = blockIdx.x * 256 + threadIdx.x;
    const int stride = gridDim.x * 256;
    for (int i = i0; i < 32768; i += stride)
        ((float4*)Z)[i] = make_float4(0.f, 0.f, 0.f, 0.f);
    for (int i = i0; i < 65536; i += stride) {
        float4 v = ((const float4*)W1)[i];
        ushort4 o; o.x = f2bf(v.x); o.y = f2bf(v.y); o.z = f2bf(v.z); o.w = f2bf(v.w);
        ((ushort4*)W1b)[i] = o;
    }
    for (int i = i0; i < 65536; i += stride) {
        float4 v = ((const float4*)W2)[i];
        ushort4 o; o.x = f2bf(v.x); o.y = f2bf(v.y); o.z = f2bf(v.z); o.w = f2bf(v.w);
        ((ushort4*)W2b)[i] = o;
    }
}

// ---------------- NT GEMM, 2-phase counted-vmcnt pipeline ----------------
// C[m][n] = sum_k A[m][k]*B[n][k]
// AF32: A is f32 (layer-1 x), staged as f32, cvt->bf16 at ds_read.
// MODE 0: write bf16 H^T per graph (g=blockIdx.x): HT[g][n][node]; fused scores -> ss/sd
// MODE 1: write bf16 gelu(C + bias[n]) row-major [m][n]
// MODE 2: write f32 (C + bias[n]) * timemask row-major
template<int KTOT, int MODE, int AF32>
__global__ __launch_bounds__(256) void gemm2(
    const void* __restrict__ Av, const u16* __restrict__ Bv,
    long aBatch, long bBatch,
    u16* __restrict__ outU, float* __restrict__ outF,
    const float* __restrict__ bias, const int* __restrict__ valid,
    const float* __restrict__ a_s, const float* __restrict__ a_d,
    float* __restrict__ ss, float* __restrict__ sd)
{
    constexpr int NT = KTOT / 32;
    __shared__ __align__(16) u16 Bs[2][128 * 32];
    __shared__ __align__(16) char Asraw[2][AF32 ? 128 * 32 * 4 : 128 * 32 * 2];
    __shared__ float sA[(MODE == 0) ? 128 : 1], dA[(MODE == 0) ? 128 : 1];

    const int tid  = threadIdx.x;
    const int lane = tid & 63;
    const int w    = tid >> 6;
    const int wm   = w & 1, wn = w >> 1;
    const int z    = blockIdx.z;
    const int g    = blockIdx.x;
    const int tm   = blockIdx.x * 128;
    const int tn   = blockIdx.y * 128;

    if (MODE == 0 && tid < 128) { sA[tid] = 0.f; dA[tid] = 0.f; }

    // ---- staging address setup (pre-swizzled global source, linear LDS dest) ----
    const int l3 = lane >> 3, l7 = lane & 7;
    // B (bf16, pair-row swizzle: 16B-block c' = c ^ (pair&7))
    const int csB = l7 ^ l3;
    const u16* Bg = Bv + (size_t)z * bBatch
                  + (size_t)(tn + w * 32 + 2 * l3 + (csB >> 2)) * KTOT + (csB & 3) * 8;
    // A
    const float* AgF = nullptr;
    const u16*   AgH = nullptr;
    if constexpr (AF32) {
        // f32 rows (128B = 8 x 16B blocks): block c' = c ^ (row&7)
        AgF = (const float*)Av + (size_t)tm * KTOT
            + (size_t)(w * 32 + l3) * KTOT + (l7 ^ l3) * 4;
    } else {
        const int csA = l7 ^ l3;
        AgH = (const u16*)Av + (size_t)z * aBatch + (size_t)tm * KTOT
            + (size_t)(w * 32 + 2 * l3 + (csA >> 2)) * KTOT + (csA & 3) * 8;
    }

    auto STAGE = [&](int buf, int t) {
        if constexpr (AF32) {
            float* Ad = (float*)Asraw[buf] + w * 1024;
            const float* Ag = AgF + t * 32;
            #pragma unroll
            for (int q = 0; q < 4; ++q)
                GLOAD16(Ag + (size_t)q * 8 * KTOT, Ad + q * 256);
        } else {
            u16* Ad = (u16*)Asraw[buf] + w * 1024;
            const u16* Ag = AgH + t * 32;
            #pragma unroll
            for (int q = 0; q < 2; ++q)
                GLOAD16(Ag + (size_t)q * 16 * KTOT, Ad + q * 512);
        }
        u16* Bd = &Bs[buf][w * 1024];
        const u16* Bg2 = Bg + t * 32;
        #pragma unroll
        for (int q = 0; q < 2; ++q)
            GLOAD16(Bg2 + (size_t)q * 16 * KTOT, Bd + q * 512);
    };

    // ---- fragment read offsets (lane-constant, swizzle folded in) ----
    const int fr = lane & 15, grp = lane >> 4;
    int boff[4], aoff1[4], aoff2[4];
    {
        int cswzB = (((fr & 1) << 2) | grp) ^ ((fr >> 1) & 7);
        #pragma unroll
        for (int j = 0; j < 4; ++j)
            boff[j] = (wn * 32 + j * 8 + (fr >> 1)) * 64 + cswzB * 8;
    }
    if constexpr (AF32) {
        #pragma unroll
        for (int i = 0; i < 4; ++i) {
            int r = wm * 64 + i * 16 + fr;
            aoff1[i] = r * 32 + (((grp * 2)     ^ (fr & 7)) * 4);
            aoff2[i] = r * 32 + (((grp * 2 + 1) ^ (fr & 7)) * 4);
        }
    } else {
        int cswzA = (((fr & 1) << 2) | grp) ^ ((fr >> 1) & 7);
        #pragma unroll
        for (int i = 0; i < 4; ++i)
            aoff1[i] = (wm * 32 + i * 8 + (fr >> 1)) * 64 + cswzA * 8;
    }

    f32x4 acc[4][4] = {};

    STAGE(0, 0);
    STAGE(1, 1);
    if constexpr (AF32) { WAITV(6); } else { WAITV(4); }
    BARRIER;

    for (int t = 0; t < NT; ++t) {
        const int cur = t & 1;
        bf16x8 af[4], bf[4];
        if constexpr (AF32) {
            const float* Ab = (const float*)Asraw[cur];
            #pragma unroll
            for (int i = 0; i < 4; ++i) {
                f32x4 lo = *(const f32x4*)&Ab[aoff1[i]];
                f32x4 hi = *(const f32x4*)&Ab[aoff2[i]];
                af[i][0] = (__bf16)lo[0]; af[i][1] = (__bf16)lo[1];
                af[i][2] = (__bf16)lo[2]; af[i][3] = (__bf16)lo[3];
                af[i][4] = (__bf16)hi[0]; af[i][5] = (__bf16)hi[1];
                af[i][6] = (__bf16)hi[2]; af[i][7] = (__bf16)hi[3];
            }
        } else {
            const u16* Ab = (const u16*)Asraw[cur];
            #pragma unroll
            for (int i = 0; i < 4; ++i)
                af[i] = *(const bf16x8*)&Ab[aoff1[i]];
        }
        {
            const u16* Bb = &Bs[cur][0];
            #pragma unroll
            for (int j = 0; j < 4; ++j)
                bf[j] = *(const bf16x8*)&Bb[boff[j]];
        }

        WAITL0;      // all this wave's ds_reads landed in regs
        BARRIER;     // all waves done reading buf[cur] -> safe to re-stage it
        if (t + 2 < NT) STAGE(cur, t + 2);

        #pragma unroll
        for (int i = 0; i < 4; ++i)
            #pragma unroll
            for (int j = 0; j < 4; ++j)
                acc[i][j] = __builtin_amdgcn_mfma_f32_16x16x32_bf16(af[i], bf[j], acc[i][j], 0, 0, 0);

        if (t + 2 < NT) {
            if constexpr (AF32) { WAITV(6); } else { WAITV(4); }   // buf[cur^1] (tile t+1) landed
        } else {
            WAITV(0);
        }
        BARRIER;
    }

    const int crow = grp * 4;
    const int ccol = fr;

    if (MODE == 0) {
        // H^T write: HT[g][n][node]
        u16* H = outU + (size_t)g * (512 * 128);
        #pragma unroll
        for (int i = 0; i < 4; ++i) {
            int node0 = wm * 64 + i * 16 + crow;
            #pragma unroll
            for (int j = 0; j < 4; ++j) {
                int n = tn + wn * 64 + j * 16 + ccol;
                ushort4 o;
                o.x = f2bf(acc[i][j][0]);
                o.y = f2bf(acc[i][j][1]);
                o.z = f2bf(acc[i][j][2]);
                o.w = f2bf(acc[i][j][3]);
                *(ushort4*)&H[(size_t)n * 128 + node0] = o;
            }
        }
        // ---- fused attention scores via shfl reduction ----
        float fsv[4], fdv[4];
        #pragma unroll
        for (int j = 0; j < 4; ++j) {
            int f = tn + wn * 64 + j * 16 + ccol;
            fsv[j] = a_s[f]; fdv[j] = a_d[f];
        }
        #pragma unroll
        for (int i = 0; i < 4; ++i)
            #pragma unroll
            for (int jj = 0; jj < 4; ++jj) {
                float s = 0.f, d = 0.f;
                #pragma unroll
                for (int j = 0; j < 4; ++j) {
                    s += acc[i][j][jj] * fsv[j];
                    d += acc[i][j][jj] * fdv[j];
                }
                #pragma unroll
                for (int off = 1; off < 16; off <<= 1) {
                    s += __shfl_xor(s, off);
                    d += __shfl_xor(d, off);
                }
                if ((lane & 15) == 0) {
                    int row = wm * 64 + i * 16 + grp * 4 + jj;
                    atomicAdd(&sA[row], s);
                    atomicAdd(&dA[row], d);
                }
            }
        __syncthreads();
        if (tid < 128) {
            atomicAdd(&ss[g * 128 + tid], sA[tid]);
            atomicAdd(&sd[g * 128 + tid], dA[tid]);
        }
    } else if (MODE == 1) {
        #pragma unroll
        for (int i = 0; i < 4; ++i) {
            int m0 = z * 128 + wm * 64 + i * 16 + crow;
            #pragma unroll
            for (int j = 0; j < 4; ++j) {
                int n = tn + wn * 64 + j * 16 + ccol;
                float bv = bias[n];
                #pragma unroll
                for (int jj = 0; jj < 4; ++jj) {
                    float v = gelu_f(acc[i][j][jj] + bv);
                    outU[(size_t)(m0 + jj) * 512 + n] = f2bf(v);
                }
            }
        }
    } else {
        int b = z >> 5, t = z & 31;
        float msk = (t < valid[b]) ? 1.0f : 0.0f;
        #pragma unroll
        for (int i = 0; i < 4; ++i) {
            int m0 = z * 128 + wm * 64 + i * 16 + crow;
            #pragma unroll
            for (int j = 0; j < 4; ++j) {
                int n = tn + wn * 64 + j * 16 + ccol;
                float bv = bias[n];
                #pragma unroll
                for (int jj = 0; jj < 4; ++jj) {
                    outF[(size_t)(m0 + jj) * 512 + n] = (acc[i][j][jj] + bv) * msk;
                }
            }
        }
    }
}

// ---------------- dense per-graph softmax -> bf16 alpha[dst][src] ----------------
__global__ __launch_bounds__(256) void alpha_kernel(const int* __restrict__ ei,
                                                    const float* __restrict__ ss,
                                                    const float* __restrict__ sd,
                                                    u16* __restrict__ alpha) {
    __shared__ float cnt[128 * 128];   // 64 KB
    __shared__ float s_s[128], s_d[128];
    int z = blockIdx.x, tid = threadIdx.x;
    for (int i = tid; i < 4096; i += 256)
        ((float4*)cnt)[i] = make_float4(0.f, 0.f, 0.f, 0.f);
    if (tid < 128) {
        s_s[tid] = ss[z * 128 + tid];
        s_d[tid] = sd[z * 128 + tid];
    }
    __syncthreads();
    const int4* es = (const int4*)(ei + (size_t)z * 4096);
    for (int i = tid; i < 512; i += 256) {
        int4 s4 = es[i];
        int4 d4 = es[512 + i];
        atomicAdd(&cnt[d4.x * 128 + s4.x], 1.0f);
        atomicAdd(&cnt[d4.y * 128 + s4.y], 1.0f);
        atomicAdd(&cnt[d4.z * 128 + s4.z], 1.0f);
        atomicAdd(&cnt[d4.w * 128 + s4.w], 1.0f);
    }
    if (tid < 128) atomicAdd(&cnt[tid * 128 + tid], 1.0f);  // self loop
    __syncthreads();
    int lane = tid & 63, wv = tid >> 6;
    for (int d = wv; d < 128; d += 4) {
        float sdv = s_d[d];
        float c0 = cnt[d * 128 + lane], c1 = cnt[d * 128 + 64 + lane];
        float e0 = s_s[lane] + sdv;       e0 = e0 > 0.f ? e0 : 0.2f * e0;
        float e1 = s_s[64 + lane] + sdv;  e1 = e1 > 0.f ? e1 : 0.2f * e1;
        float m = fmaxf(c0 > 0.f ? e0 : -1e30f, c1 > 0.f ? e1 : -1e30f);
        #pragma unroll
        for (int o = 32; o; o >>= 1) m = fmaxf(m, __shfl_xor(m, o));
        float p0 = c0 > 0.f ? c0 * __expf(e0 - m) : 0.f;
        float p1 = c1 > 0.f ? c1 * __expf(e1 - m) : 0.f;
        float sum = p0 + p1;
        #pragma unroll
        for (int o = 32; o; o >>= 1) sum += __shfl_xor(sum, o);
        float inv = 1.f / sum;
        alpha[(size_t)z * 16384 + d * 128 + lane]      = f2bf(p0 * inv);
        alpha[(size_t)z * 16384 + d * 128 + 64 + lane] = f2bf(p1 * inv);
    }
}

// ---------------- time mix: out = gelu(W_time @ y + b_time) + y, in-place ----------------
__global__ __launch_bounds__(256) void timemix_kernel(float* __restrict__ y,
                                                      const float* __restrict__ Wt,
                                                      const float* __restrict__ bt) {
    __shared__ float wsm[1024];
    __shared__ float bts[32];
    int tid = threadIdx.x;
    for (int i = tid; i < 1024; i += 256) wsm[i] = Wt[i];
    if (tid < 32) bts[tid] = bt[tid];
    __syncthreads();
    int blk = blockIdx.x;               // 2048 blocks
    int b = blk >> 8;
    int rem = blk & 255;
    int n = rem >> 1;
    int f = (rem & 1) * 256 + tid;
    size_t base = ((size_t)b * 4096 + n) * 512 + f;   // (b,0,n,f); s-stride = 65536
    float ys[32];
    #pragma unroll
    for (int s = 0; s < 32; ++s) ys[s] = y[base + (size_t)s * 65536];
    #pragma unroll
    for (int t = 0; t < 32; ++t) {
        float a = bts[t];
        #pragma unroll
        for (int s = 0; s < 32; ++s) a += wsm[t * 32 + s] * ys[s];
        y[base + (size_t)t * 65536] = gelu_f(a) + ys[t];
    }
}

extern "C" void kernel_launch(void* const* d_in, const int* in_sizes, int n_in,
                              void* d_out, int out_size, void* d_ws, size_t ws_size,
                              hipStream_t stream) {
    const float* x     = (const float*)d_in[0];
    const int*   ei    = (const int*)d_in[1];
    const int*   valid = (const int*)d_in[2];
    const float* W1    = (const float*)d_in[3];
    const float* a1s   = (const float*)d_in[4];
    const float* a1d   = (const float*)d_in[5];
    const float* b1    = (const float*)d_in[6];
    const float* W2    = (const float*)d_in[7];
    const float* a2s   = (const float*)d_in[8];
    const float* a2d   = (const float*)d_in[9];
    const float* b2    = (const float*)d_in[10];
    const float* Wt    = (const float*)d_in[11];
    const float* bt    = (const float*)d_in[12];
    float* out = (float*)d_out;

    char* ws = (char*)d_ws;
    u16* Xb   = (u16*)(ws);                       // 33,554,432 B (gelu(h1) bf16)
    u16* HTb  = (u16*)(ws + 33554432);            // 33,554,432 B
    u16* ALPH = (u16*)(ws + 67108864);            //  8,388,608 B
    u16* W1b  = (u16*)(ws + 75497472);            //    524,288 B
    u16* W2b  = (u16*)(ws + 76021760);            //    524,288 B
    float* SS1 = (float*)(ws + 76546048);         //    131,072 B  (zeroed by prep)
    float* SD1 = (float*)(ws + 76677120);         //    131,072 B
    float* SS2 = (float*)(ws + 76808192);         //    131,072 B
    float* SD2 = (float*)(ws + 76939264);         //    131,072 B

    prep_kernel<<<256, 256, 0, stream>>>(W1, W2, W1b, W2b, SS1);

    // ---- layer 1 (A = x, f32 staged) ----
    gemm2<512, 0, 1><<<dim3(256, 4, 1), 256, 0, stream>>>(x, W1b, 0, 0, HTb, nullptr,
        nullptr, nullptr, a1s, a1d, SS1, SD1);
    alpha_kernel<<<256, 256, 0, stream>>>(ei, SS1, SD1, ALPH);
    gemm2<128, 1, 0><<<dim3(1, 4, 256), 256, 0, stream>>>(ALPH, HTb, 16384, 65536, Xb, nullptr,
        b1, nullptr, nullptr, nullptr, nullptr, nullptr);

    // ---- layer 2 ----
    gemm2<512, 0, 0><<<dim3(256, 4, 1), 256, 0, stream>>>(Xb, W2b, 0, 0, HTb, nullptr,
        nullptr, nullptr, a2s, a2d, SS2, SD2);
    alpha_kernel<<<256, 256, 0, stream>>>(ei, SS2, SD2, ALPH);
    gemm2<128, 2, 0><<<dim3(1, 4, 256), 256, 0, stream>>>(ALPH, HTb, 16384, 65536, nullptr, out,
        b2, valid, nullptr, nullptr, nullptr, nullptr);

    // ---- time mixing (in-place on d_out) ----
    timemix_kernel<<<2048, 256, 0, stream>>>(out, Wt, bt);
}

// Round 6
// 198.943 us; speedup vs baseline: 1.7370x; 1.0890x over previous
//
#include <hip/hip_runtime.h>

using u16 = unsigned short;
using u32 = unsigned int;

typedef __bf16 bf16x8 __attribute__((ext_vector_type(8)));
typedef float  f32x4  __attribute__((ext_vector_type(4)));

__device__ __forceinline__ u16 f2bf(float f) {
    u32 u = __float_as_uint(f);
    u32 r = u + 0x7fffu + ((u >> 16) & 1u);
    return (u16)(r >> 16);
}
__device__ __forceinline__ float gelu_f(float x) {
    return 0.5f * x * (1.0f + erff(x * 0.70710678118654752440f));
}

#define GLOAD16(gp, lp) __builtin_amdgcn_global_load_lds( \
    (const __attribute__((address_space(1))) void*)(gp),  \
    (__attribute__((address_space(3))) void*)(lp), 16, 0, 0)
#define WAITV0  asm volatile("s_waitcnt vmcnt(0)" ::: "memory")
#define WAITL0  asm volatile("s_waitcnt lgkmcnt(0)" ::: "memory")
#define BARRIER __builtin_amdgcn_s_barrier()

// ---------------- prep: cvt W1/W2 to bf16 with bank-swizzle baked in ----------------
// W'[f][ (k&~31) | ((((k>>3)&3) ^ (f&3))<<3) | (k&7) ] = W[f][k]
__global__ __launch_bounds__(256) void prep_kernel(
    const float* __restrict__ W1, const float* __restrict__ W2,
    u16* __restrict__ W1b, u16* __restrict__ W2b)
{
    int i = blockIdx.x * 256 + threadIdx.x;          // 0..131071
    const float* src = (i < 65536) ? W1 : W2;
    u16* dst = (i < 65536) ? W1b : W2b;
    int ii = i & 65535;
    int f = ii >> 7;
    int k = (ii & 127) * 4;
    float4 v = ((const float4*)src)[ii];
    int kd = (k & ~31) | ((((k >> 3) & 3) ^ (f & 3)) << 3) | (k & 7);
    ushort4 o;
    o.x = f2bf(v.x); o.y = f2bf(v.y); o.z = f2bf(v.z); o.w = f2bf(v.w);
    *(ushort4*)&dst[f * 512 + kd] = o;
}

// ---------------- mega: full 2-layer GAT per graph, 1 block/graph ----------------
// LDS map: Hs[65536] u16 (128KB): H1^T[512][128] -> H1'[128][512] -> H2^T[512][128]
// SG[16384] u16 (32KB): bytes [0,8192) x-tile | [8192,24576) W half-tiles (8 waves x 2KB)
//                       bytes [24576,26624) stats: ss[128] sd[128] M[128] rD[128]
//                       bytes [0,16384) cnt u32[128][32] (u8-packed) during AGG phases
__global__ __launch_bounds__(512, 2) void mega_kernel(
    const float* __restrict__ x, const int* __restrict__ ei, const int* __restrict__ valid,
    const u16* __restrict__ W1b, const float* __restrict__ a1s, const float* __restrict__ a1d,
    const float* __restrict__ b1,
    const u16* __restrict__ W2b, const float* __restrict__ a2s, const float* __restrict__ a2d,
    const float* __restrict__ b2,
    float* __restrict__ outF)
{
    __shared__ u16 Hs[65536];
    __shared__ __align__(16) u16 SG[16384];

    const int tid  = threadIdx.x;
    const int lane = tid & 63;
    const int w    = tid >> 6;        // wave 0..7
    const int rl   = lane & 15;
    const int grp  = lane >> 4;
    const int gid  = blockIdx.x;      // graph
    const int bb   = gid >> 5, tt = gid & 31;

    float* stf = (float*)(SG + 12288);     // stats (bytes 24576..26624)
    u32*   cntw = (u32*)SG;                // cnt   (bytes 0..16384)
    const unsigned char* cb = (const unsigned char*)SG;

    const int xr = tid >> 2, xq = tid & 3; // x staging map
    const float* xg = x + (size_t)gid * 65536;

    // =========================================================================
    // Layer loop is unrolled manually (layer 1 has x-staging; layer 2 reads Hs)
    // =========================================================================

    // ---------------- GEMM1: H1[m][f] = sum_k x[m][k] W1[f][k] ----------------
    {
        f32x4 acc[8][4] = {};
        float4 xa = *(const float4*)(xg + xr * 512 + xq * 8);
        float4 xc = *(const float4*)(xg + xr * 512 + xq * 8 + 4);
        for (int kt = 0; kt < 16; ++kt) {
            // stage W half 0 (rows w*64 .. +32)
            {
                const u16* s0 = W1b + (size_t)(w * 64 + (lane >> 2)) * 512 + kt * 32 + (lane & 3) * 8;
                GLOAD16(s0,            &SG[4096 + w * 1024]);
                GLOAD16(s0 + 16 * 512, &SG[4096 + w * 1024 + 512]);
            }
            // write x tile kt (compiler waits xa/xc)
            {
                ushort4 lo, hi;
                lo.x = f2bf(xa.x); lo.y = f2bf(xa.y); lo.z = f2bf(xa.z); lo.w = f2bf(xa.w);
                hi.x = f2bf(xc.x); hi.y = f2bf(xc.y); hi.z = f2bf(xc.z); hi.w = f2bf(xc.w);
                int xo = xr * 32 + ((xq ^ (xr & 3)) << 3);
                *(ushort4*)&SG[xo]     = lo;
                *(ushort4*)&SG[xo + 4] = hi;
            }
            WAITV0; BARRIER;
            bf16x8 af[8];
            #pragma unroll
            for (int i = 0; i < 8; ++i)
                af[i] = *(const bf16x8*)&SG[(i * 16 + rl) * 32 + ((grp ^ (rl & 3)) << 3)];
            bf16x8 bv0 = *(const bf16x8*)&SG[4096 + w * 1024 + (rl) * 32      + ((grp ^ (rl & 3)) << 3)];
            bf16x8 bv1 = *(const bf16x8*)&SG[4096 + w * 1024 + (16 + rl) * 32 + ((grp ^ (rl & 3)) << 3)];
            WAITL0; BARRIER;
            // stage W half 1 (rows w*64+32 .. +32)
            {
                const u16* s0 = W1b + (size_t)(w * 64 + 32 + (lane >> 2)) * 512 + kt * 32 + (lane & 3) * 8;
                GLOAD16(s0,            &SG[4096 + w * 1024]);
                GLOAD16(s0 + 16 * 512, &SG[4096 + w * 1024 + 512]);
            }
            #pragma unroll
            for (int i = 0; i < 8; ++i) {
                acc[i][0] = __builtin_amdgcn_mfma_f32_16x16x32_bf16(af[i], bv0, acc[i][0], 0, 0, 0);
                acc[i][1] = __builtin_amdgcn_mfma_f32_16x16x32_bf16(af[i], bv1, acc[i][1], 0, 0, 0);
            }
            WAITV0; BARRIER;
            bf16x8 bv2 = *(const bf16x8*)&SG[4096 + w * 1024 + (rl) * 32      + ((grp ^ (rl & 3)) << 3)];
            bf16x8 bv3 = *(const bf16x8*)&SG[4096 + w * 1024 + (16 + rl) * 32 + ((grp ^ (rl & 3)) << 3)];
            WAITL0;
            if (kt < 15) {  // prefetch next x tile (covered by MFMA + next stage)
                xa = *(const float4*)(xg + xr * 512 + (kt + 1) * 32 + xq * 8);
                xc = *(const float4*)(xg + xr * 512 + (kt + 1) * 32 + xq * 8 + 4);
            }
            #pragma unroll
            for (int i = 0; i < 8; ++i) {
                acc[i][2] = __builtin_amdgcn_mfma_f32_16x16x32_bf16(af[i], bv2, acc[i][2], 0, 0, 0);
                acc[i][3] = __builtin_amdgcn_mfma_f32_16x16x32_bf16(af[i], bv3, acc[i][3], 0, 0, 0);
            }
            BARRIER;
        }
        // ---- GEMM1 epilogue: zero stats; H1^T -> Hs; fused scores ----
        stf[tid] = 0.f;
        __syncthreads();
        float asv[4], adv[4];
        #pragma unroll
        for (int j = 0; j < 4; ++j) {
            int f = w * 64 + j * 16 + rl;
            asv[j] = a1s[f]; adv[j] = a1d[f];
        }
        #pragma unroll
        for (int i = 0; i < 8; ++i) {
            #pragma unroll
            for (int j = 0; j < 4; ++j) {
                int f = w * 64 + j * 16 + rl;
                ushort4 o;
                o.x = f2bf(acc[i][j][0]); o.y = f2bf(acc[i][j][1]);
                o.z = f2bf(acc[i][j][2]); o.w = f2bf(acc[i][j][3]);
                *(ushort4*)&Hs[(f * 128 + i * 16 + grp * 4) ^ ((f & 7) << 3)] = o;
            }
            #pragma unroll
            for (int r = 0; r < 4; ++r) {
                float s = acc[i][0][r] * asv[0] + acc[i][1][r] * asv[1]
                        + acc[i][2][r] * asv[2] + acc[i][3][r] * asv[3];
                float d = acc[i][0][r] * adv[0] + acc[i][1][r] * adv[1]
                        + acc[i][2][r] * adv[2] + acc[i][3][r] * adv[3];
                #pragma unroll
                for (int off = 1; off < 16; off <<= 1) {
                    s += __shfl_xor(s, off);
                    d += __shfl_xor(d, off);
                }
                if (rl == 0) {
                    atomicAdd(&stf[i * 16 + grp * 4 + r], s);
                    atomicAdd(&stf[128 + i * 16 + grp * 4 + r], d);
                }
            }
        }
        __syncthreads();
    }

    // ---------------- cnt scatter + M/D (layer 1) ----------------
    {
        for (int i = tid; i < 4096; i += 512) cntw[i] = 0u;
        __syncthreads();
        const int4* es = (const int4*)(ei + (size_t)gid * 4096);
        int4 s4 = es[tid], d4 = es[512 + tid];
        atomicAdd(&cntw[(u32)((d4.x * 32 + (s4.x >> 2)) ^ ((d4.x & 7) << 1))], 1u << (8 * (s4.x & 3)));
        atomicAdd(&cntw[(u32)((d4.y * 32 + (s4.y >> 2)) ^ ((d4.y & 7) << 1))], 1u << (8 * (s4.y & 3)));
        atomicAdd(&cntw[(u32)((d4.z * 32 + (s4.z >> 2)) ^ ((d4.z & 7) << 1))], 1u << (8 * (s4.z & 3)));
        atomicAdd(&cntw[(u32)((d4.w * 32 + (s4.w >> 2)) ^ ((d4.w & 7) << 1))], 1u << (8 * (s4.w & 3)));
        if (tid < 128)
            atomicAdd(&cntw[(u32)((tid * 32 + (tid >> 2)) ^ ((tid & 7) << 1))], 1u << (8 * (tid & 3)));
        __syncthreads();
        for (int r = 0; r < 16; ++r) {
            int m = w * 16 + r;
            float sdm = stf[128 + m];
            int s0 = lane, s1 = lane + 64;
            u32 c0 = cb[((m * 128 + (s0 & ~3)) ^ ((m & 7) << 3)) + (s0 & 3)];
            u32 c1 = cb[((m * 128 + (s1 & ~3)) ^ ((m & 7) << 3)) + (s1 & 3)];
            float e0 = stf[s0] + sdm; e0 = e0 > 0.f ? e0 : 0.2f * e0;
            float e1 = stf[s1] + sdm; e1 = e1 > 0.f ? e1 : 0.2f * e1;
            float mx = fmaxf(c0 ? e0 : -1e30f, c1 ? e1 : -1e30f);
            #pragma unroll
            for (int off = 1; off < 64; off <<= 1) mx = fmaxf(mx, __shfl_xor(mx, off));
            float p = (c0 ? (float)c0 * __expf(e0 - mx) : 0.f)
                    + (c1 ? (float)c1 * __expf(e1 - mx) : 0.f);
            #pragma unroll
            for (int off = 1; off < 64; off <<= 1) p += __shfl_xor(p, off);
            if (lane == 0) { stf[256 + m] = mx; stf[384 + m] = 1.f / p; }
        }
        __syncthreads();
    }

    // ---------------- AGG1: H1'[m][f] = gelu( sum_s alpha[m][s] H1[s][f] + b1 ) ----------------
    {
        f32x4 acc2[32] = {};
        int m = w * 16 + rl;
        float Mm = stf[256 + m], rDm = stf[384 + m], sdm = stf[128 + m];
        bf16x8 pa[4];
        #pragma unroll
        for (int kb = 0; kb < 4; ++kb) {
            u32 wi = (u32)((m * 32 + kb * 8 + grp * 2) ^ ((m & 7) << 1));
            u32 w0 = cntw[wi], w1 = cntw[wi + 1];
            #pragma unroll
            for (int e = 0; e < 8; ++e) {
                int s = kb * 32 + grp * 8 + e;
                u32 c = ((e < 4 ? (w0 >> (8 * e)) : (w1 >> (8 * (e - 4)))) & 255u);
                float ev = stf[s] + sdm; ev = ev > 0.f ? ev : 0.2f * ev;
                float p = c ? (float)c * __expf(ev - Mm) * rDm : 0.f;
                pa[kb][e] = (__bf16)p;
            }
        }
        #pragma unroll
        for (int j = 0; j < 32; ++j) {
            int f = j * 16 + rl;
            #pragma unroll
            for (int kb = 0; kb < 4; ++kb) {
                bf16x8 hb = *(const bf16x8*)&Hs[(f * 128 + kb * 32 + grp * 8) ^ ((f & 7) << 3)];
                acc2[j] = __builtin_amdgcn_mfma_f32_16x16x32_bf16(pa[kb], hb, acc2[j], 0, 0, 0);
            }
        }
        __syncthreads();   // all H1^T reads done before overwrite
        #pragma unroll
        for (int j = 0; j < 32; ++j) {
            int f = j * 16 + rl;
            float bv = b1[f];
            #pragma unroll
            for (int r = 0; r < 4; ++r) {
                int mm = w * 16 + grp * 4 + r;
                Hs[(mm * 512 + f) ^ ((mm & 7) << 3)] = f2bf(gelu_f(acc2[j][r] + bv));
            }
        }
        __syncthreads();
    }

    // ---------------- GEMM2: H2[m][g] = sum_f H1'[m][f] W2[g][f] ----------------
    {
        f32x4 acc[8][4] = {};
        for (int kt = 0; kt < 16; ++kt) {
            {
                const u16* s0 = W2b + (size_t)(w * 64 + (lane >> 2)) * 512 + kt * 32 + (lane & 3) * 8;
                GLOAD16(s0,            &SG[4096 + w * 1024]);
                GLOAD16(s0 + 16 * 512, &SG[4096 + w * 1024 + 512]);
            }
            WAITV0; BARRIER;
            bf16x8 af[8];
            #pragma unroll
            for (int i = 0; i < 8; ++i)
                af[i] = *(const bf16x8*)&Hs[((i * 16 + rl) * 512 + kt * 32 + grp * 8) ^ ((rl & 7) << 3)];
            bf16x8 bv0 = *(const bf16x8*)&SG[4096 + w * 1024 + (rl) * 32      + ((grp ^ (rl & 3)) << 3)];
            bf16x8 bv1 = *(const bf16x8*)&SG[4096 + w * 1024 + (16 + rl) * 32 + ((grp ^ (rl & 3)) << 3)];
            WAITL0; BARRIER;
            {
                const u16* s0 = W2b + (size_t)(w * 64 + 32 + (lane >> 2)) * 512 + kt * 32 + (lane & 3) * 8;
                GLOAD16(s0,            &SG[4096 + w * 1024]);
                GLOAD16(s0 + 16 * 512, &SG[4096 + w * 1024 + 512]);
            }
            #pragma unroll
            for (int i = 0; i < 8; ++i) {
                acc[i][0] = __builtin_amdgcn_mfma_f32_16x16x32_bf16(af[i], bv0, acc[i][0], 0, 0, 0);
                acc[i][1] = __builtin_amdgcn_mfma_f32_16x16x32_bf16(af[i], bv1, acc[i][1], 0, 0, 0);
            }
            WAITV0; BARRIER;
            bf16x8 bv2 = *(const bf16x8*)&SG[4096 + w * 1024 + (rl) * 32      + ((grp ^ (rl & 3)) << 3)];
            bf16x8 bv3 = *(const bf16x8*)&SG[4096 + w * 1024 + (16 + rl) * 32 + ((grp ^ (rl & 3)) << 3)];
            WAITL0;
            #pragma unroll
            for (int i = 0; i < 8; ++i) {
                acc[i][2] = __builtin_amdgcn_mfma_f32_16x16x32_bf16(af[i], bv2, acc[i][2], 0, 0, 0);
                acc[i][3] = __builtin_amdgcn_mfma_f32_16x16x32_bf16(af[i], bv3, acc[i][3], 0, 0, 0);
            }
            BARRIER;
        }
        // ---- GEMM2 epilogue: zero stats; H2^T -> Hs; fused scores2 ----
        stf[tid] = 0.f;
        __syncthreads();
        float asv[4], adv[4];
        #pragma unroll
        for (int j = 0; j < 4; ++j) {
            int f = w * 64 + j * 16 + rl;
            asv[j] = a2s[f]; adv[j] = a2d[f];
        }
        #pragma unroll
        for (int i = 0; i < 8; ++i) {
            #pragma unroll
            for (int j = 0; j < 4; ++j) {
                int f = w * 64 + j * 16 + rl;
                ushort4 o;
                o.x = f2bf(acc[i][j][0]); o.y = f2bf(acc[i][j][1]);
                o.z = f2bf(acc[i][j][2]); o.w = f2bf(acc[i][j][3]);
                *(ushort4*)&Hs[(f * 128 + i * 16 + grp * 4) ^ ((f & 7) << 3)] = o;
            }
            #pragma unroll
            for (int r = 0; r < 4; ++r) {
                float s = acc[i][0][r] * asv[0] + acc[i][1][r] * asv[1]
                        + acc[i][2][r] * asv[2] + acc[i][3][r] * asv[3];
                float d = acc[i][0][r] * adv[0] + acc[i][1][r] * adv[1]
                        + acc[i][2][r] * adv[2] + acc[i][3][r] * adv[3];
                #pragma unroll
                for (int off = 1; off < 16; off <<= 1) {
                    s += __shfl_xor(s, off);
                    d += __shfl_xor(d, off);
                }
                if (rl == 0) {
                    atomicAdd(&stf[i * 16 + grp * 4 + r], s);
                    atomicAdd(&stf[128 + i * 16 + grp * 4 + r], d);
                }
            }
        }
        __syncthreads();
    }

    // ---------------- cnt re-scatter + M/D (layer 2; W staging destroyed cnt) ----------------
    {
        for (int i = tid; i < 4096; i += 512) cntw[i] = 0u;
        __syncthreads();
        const int4* es = (const int4*)(ei + (size_t)gid * 4096);
        int4 s4 = es[tid], d4 = es[512 + tid];
        atomicAdd(&cntw[(u32)((d4.x * 32 + (s4.x >> 2)) ^ ((d4.x & 7) << 1))], 1u << (8 * (s4.x & 3)));
        atomicAdd(&cntw[(u32)((d4.y * 32 + (s4.y >> 2)) ^ ((d4.y & 7) << 1))], 1u << (8 * (s4.y & 3)));
        atomicAdd(&cntw[(u32)((d4.z * 32 + (s4.z >> 2)) ^ ((d4.z & 7) << 1))], 1u << (8 * (s4.z & 3)));
        atomicAdd(&cntw[(u32)((d4.w * 32 + (s4.w >> 2)) ^ ((d4.w & 7) << 1))], 1u << (8 * (s4.w & 3)));
        if (tid < 128)
            atomicAdd(&cntw[(u32)((tid * 32 + (tid >> 2)) ^ ((tid & 7) << 1))], 1u << (8 * (tid & 3)));
        __syncthreads();
        for (int r = 0; r < 16; ++r) {
            int m = w * 16 + r;
            float sdm = stf[128 + m];
            int s0 = lane, s1 = lane + 64;
            u32 c0 = cb[((m * 128 + (s0 & ~3)) ^ ((m & 7) << 3)) + (s0 & 3)];
            u32 c1 = cb[((m * 128 + (s1 & ~3)) ^ ((m & 7) << 3)) + (s1 & 3)];
            float e0 = stf[s0] + sdm; e0 = e0 > 0.f ? e0 : 0.2f * e0;
            float e1 = stf[s1] + sdm; e1 = e1 > 0.f ? e1 : 0.2f * e1;
            float mx = fmaxf(c0 ? e0 : -1e30f, c1 ? e1 : -1e30f);
            #pragma unroll
            for (int off = 1; off < 64; off <<= 1) mx = fmaxf(mx, __shfl_xor(mx, off));
            float p = (c0 ? (float)c0 * __expf(e0 - mx) : 0.f)
                    + (c1 ? (float)c1 * __expf(e1 - mx) : 0.f);
            #pragma unroll
            for (int off = 1; off < 64; off <<= 1) p += __shfl_xor(p, off);
            if (lane == 0) { stf[256 + m] = mx; stf[384 + m] = 1.f / p; }
        }
        __syncthreads();
    }

    // ---------------- AGG2 + masked f32 output ----------------
    {
        f32x4 acc2[32] = {};
        int m = w * 16 + rl;
        float Mm = stf[256 + m], rDm = stf[384 + m], sdm = stf[128 + m];
        bf16x8 pa[4];
        #pragma unroll
        for (int kb = 0; kb < 4; ++kb) {
            u32 wi = (u32)((m * 32 + kb * 8 + grp * 2) ^ ((m & 7) << 1));
            u32 w0 = cntw[wi], w1 = cntw[wi + 1];
            #pragma unroll
            for (int e = 0; e < 8; ++e) {
                int s = kb * 32 + grp * 8 + e;
                u32 c = ((e < 4 ? (w0 >> (8 * e)) : (w1 >> (8 * (e - 4)))) & 255u);
                float ev = stf[s] + sdm; ev = ev > 0.f ? ev : 0.2f * ev;
                float p = c ? (float)c * __expf(ev - Mm) * rDm : 0.f;
                pa[kb][e] = (__bf16)p;
            }
        }
        #pragma unroll
        for (int j = 0; j < 32; ++j) {
            int f = j * 16 + rl;
            #pragma unroll
            for (int kb = 0; kb < 4; ++kb) {
                bf16x8 hb = *(const bf16x8*)&Hs[(f * 128 + kb * 32 + grp * 8) ^ ((f & 7) << 3)];
                acc2[j] = __builtin_amdgcn_mfma_f32_16x16x32_bf16(pa[kb], hb, acc2[j], 0, 0, 0);
            }
        }
        float msk = (tt < valid[bb]) ? 1.f : 0.f;
        float* og = outF + (size_t)gid * 65536;
        #pragma unroll
        for (int j = 0; j < 32; ++j) {
            int g = j * 16 + rl;
            float bv = b2[g];
            #pragma unroll
            for (int r = 0; r < 4; ++r)
                og[(w * 16 + grp * 4 + r) * 512 + g] = (acc2[j][r] + bv) * msk;
        }
    }
}

// ---------------- time mix: out = gelu(W_time @ y + b_time) + y, in-place ----------------
__global__ __launch_bounds__(256) void timemix_kernel(float* __restrict__ y,
                                                      const float* __restrict__ Wt,
                                                      const float* __restrict__ bt) {
    __shared__ float wsm[1024];
    __shared__ float bts[32];
    int tid = threadIdx.x;
    for (int i = tid; i < 1024; i += 256) wsm[i] = Wt[i];
    if (tid < 32) bts[tid] = bt[tid];
    __syncthreads();
    int blk = blockIdx.x;               // 2048 blocks
    int b = blk >> 8;
    int rem = blk & 255;
    int n = rem >> 1;
    int f = (rem & 1) * 256 + tid;
    size_t base = ((size_t)b * 4096 + n) * 512 + f;
    float ys[32];
    #pragma unroll
    for (int s = 0; s < 32; ++s) ys[s] = y[base + (size_t)s * 65536];
    #pragma unroll
    for (int t = 0; t < 32; ++t) {
        float a = bts[t];
        #pragma unroll
        for (int s = 0; s < 32; ++s) a += wsm[t * 32 + s] * ys[s];
        y[base + (size_t)t * 65536] = gelu_f(a) + ys[t];
    }
}

extern "C" void kernel_launch(void* const* d_in, const int* in_sizes, int n_in,
                              void* d_out, int out_size, void* d_ws, size_t ws_size,
                              hipStream_t stream) {
    const float* x     = (const float*)d_in[0];
    const int*   ei    = (const int*)d_in[1];
    const int*   valid = (const int*)d_in[2];
    const float* W1    = (const float*)d_in[3];
    const float* a1s   = (const float*)d_in[4];
    const float* a1d   = (const float*)d_in[5];
    const float* b1    = (const float*)d_in[6];
    const float* W2    = (const float*)d_in[7];
    const float* a2s   = (const float*)d_in[8];
    const float* a2d   = (const float*)d_in[9];
    const float* b2    = (const float*)d_in[10];
    const float* Wt    = (const float*)d_in[11];
    const float* bt    = (const float*)d_in[12];
    float* out = (float*)d_out;

    char* ws = (char*)d_ws;
    u16* W1b = (u16*)(ws);            // 524,288 B (bf16, bank-swizzled)
    u16* W2b = (u16*)(ws + 524288);   // 524,288 B

    prep_kernel<<<512, 256, 0, stream>>>(W1, W2, W1b, W2b);
    mega_kernel<<<256, 512, 0, stream>>>(x, ei, valid,
        W1b, a1s, a1d, b1, W2b, a2s, a2d, b2, out);
    timemix_kernel<<<2048, 256, 0, stream>>>(out, Wt, bt);
}